// Round 1
// baseline (52.733 us; speedup 1.0000x reference)
//
#include <hip/hip_runtime.h>

namespace {
constexpr int kB = 16384;
constexpr int kC = 1000;
constexpr int kNElem = kB * kC;          // 16,384,000
constexpr int kNV4 = kNElem / 4;         // 4,096,000
constexpr int kV4PerRow = kC / 4;        // 250
constexpr int kBlocks = 1024;
constexpr int kThreads = 256;
}

// ws layout (19 x 4B):
//   wsf[0..8]  : float cum_j  = sum of bce over elements with s >= t_j   (j=1..9)
//   wsf[9]     : float T      = sum of bce over all elements
//   wsu[10..18]: uint  cnt_j  = count of elements with s >= t_j          (j=1..9)

__global__ __launch_bounds__(kThreads) void ghmc_main(
    const float* __restrict__ logits,
    const int* __restrict__ tgt,
    float* __restrict__ wsf)
{
    // t_j = logit(j/10) = ln(j/(10-j)), j = 1..9
    constexpr float th[9] = {
        -2.19722458f, -1.38629436f, -0.84729786f, -0.40546511f, 0.0f,
         0.40546511f,  0.84729786f,  1.38629436f,  2.19722458f};

    float cum[9] = {0.f,0.f,0.f,0.f,0.f,0.f,0.f,0.f,0.f};
    unsigned cnt[9] = {0u,0u,0u,0u,0u,0u,0u,0u,0u};
    float T = 0.f;

    const int stride = gridDim.x * blockDim.x;
    for (int i = blockIdx.x * blockDim.x + threadIdx.x; i < kNV4; i += stride) {
        const int row   = i / kV4PerRow;             // magic-mul division
        const int cbase = (i - row * kV4PerRow) * 4;
        const int t     = tgt[row];                  // L1-resident (64 KB array)
        const float4 v  = reinterpret_cast<const float4*>(logits)[i];
        const float lv[4] = {v.x, v.y, v.z, v.w};
        #pragma unroll
        for (int e = 0; e < 4; ++e) {
            const float L   = lv[e];
            const bool  ist = (cbase + e) == t;
            const float s   = ist ? -L : L;          // g = sigmoid(s)
            const float en  = __expf(-fabsf(L));     // exp(-|l|)
            // bce = max(l,0) - l*t + log1p(exp(-|l|))
            const float bce = fmaxf(L, 0.f) - (ist ? L : 0.f) + __logf(1.f + en);
            T += bce;
            #pragma unroll
            for (int j = 0; j < 9; ++j) {
                const bool m = (s >= th[j]);
                cum[j] += m ? bce : 0.f;
                cnt[j] += (unsigned)m;
            }
        }
    }

    // 64-lane wave reduction
    #pragma unroll
    for (int off = 32; off > 0; off >>= 1) {
        T += __shfl_down(T, off);
        #pragma unroll
        for (int j = 0; j < 9; ++j) {
            cum[j] += __shfl_down(cum[j], off);
            cnt[j] += __shfl_down(cnt[j], off);
        }
    }

    __shared__ float    s_f[kThreads / 64][10];
    __shared__ unsigned s_u[kThreads / 64][9];
    const int wave = threadIdx.x >> 6;
    const int lane = threadIdx.x & 63;
    if (lane == 0) {
        #pragma unroll
        for (int j = 0; j < 9; ++j) { s_f[wave][j] = cum[j]; s_u[wave][j] = cnt[j]; }
        s_f[wave][9] = T;
    }
    __syncthreads();
    if (threadIdx.x < 10) {
        const int j = threadIdx.x;
        const float v = s_f[0][j] + s_f[1][j] + s_f[2][j] + s_f[3][j];
        atomicAdd(&wsf[j], v);
    } else if (threadIdx.x < 19) {
        const int j = threadIdx.x - 10;
        const unsigned v = s_u[0][j] + s_u[1][j] + s_u[2][j] + s_u[3][j];
        atomicAdd(reinterpret_cast<unsigned*>(wsf) + 10 + j, v);
    }
}

__global__ void ghmc_final(const float* __restrict__ wsf, float* __restrict__ out)
{
    if (threadIdx.x == 0 && blockIdx.x == 0) {
        const unsigned* wsu = reinterpret_cast<const unsigned*>(wsf);
        float cumk[11], cntk[11];
        cumk[0] = wsf[9];                 // T: all elements
        cntk[0] = (float)kNElem;
        #pragma unroll
        for (int j = 1; j <= 9; ++j) {
            cumk[j] = wsf[j - 1];
            cntk[j] = (float)wsu[9 + j];
        }
        cumk[10] = 0.f; cntk[10] = 0.f;
        float acc = 0.f, n = 0.f;
        #pragma unroll
        for (int k = 0; k < 10; ++k) {
            const float Nk = cntk[k] - cntk[k + 1];
            if (Nk > 0.f) {
                n += 1.f;
                acc += (cumk[k] - cumk[k + 1]) / Nk;
            }
        }
        out[0] = acc / fmaxf(n, 1.f);     // LOSS_WEIGHT = 1
    }
}

extern "C" void kernel_launch(void* const* d_in, const int* in_sizes, int n_in,
                              void* d_out, int out_size, void* d_ws, size_t ws_size,
                              hipStream_t stream)
{
    const float* logits = (const float*)d_in[0];
    const int*   tgt    = (const int*)d_in[1];
    float* wsf = (float*)d_ws;
    hipMemsetAsync(d_ws, 0, 19 * sizeof(float), stream);
    ghmc_main<<<kBlocks, kThreads, 0, stream>>>(logits, tgt, wsf);
    ghmc_final<<<1, 64, 0, stream>>>(wsf, (float*)d_out);
}